// Round 2
// baseline (382.058 us; speedup 1.0000x reference)
//
#include <hip/hip_runtime.h>
#include <stdint.h>

// Problem dims (fixed): x[4,4096,2048] f32, W[2048,2048] f32, bias[2048] f32
#define NTOK   16384
#define DIN    2048
#define DOUT   2048
#define WELEMS (DOUT * DIN)

typedef int v4i __attribute__((ext_vector_type(4)));

// async global->LDS, 16B per lane. LDS dest must be wave-uniform base + lane*16.
__device__ __forceinline__ void load_lds16(const void* g, void* s) {
    __builtin_amdgcn_global_load_lds(
        (const __attribute__((address_space(1))) void*)(uintptr_t)g,
        (__attribute__((address_space(3))) void*)(uintptr_t)s,
        16, 0, 0);
}

__global__ void zero_ws(double* p) { p[0] = 0.0; }

// ---- kernel 1: sum |W| in fp64 (minimizes ternary-boundary flip risk) -----
__global__ __launch_bounds__(256) void wabs_sum(const float* __restrict__ w,
                                                double* __restrict__ wsum) {
    int idx = blockIdx.x * 256 + threadIdx.x;            // float4 index
    float4 r = ((const float4*)w)[idx];
    double s = (double)fabsf(r.x) + (double)fabsf(r.y) +
               (double)fabsf(r.z) + (double)fabsf(r.w);
    for (int o = 32; o; o >>= 1) s += __shfl_down(s, o);
    __shared__ double sm[4];
    if ((threadIdx.x & 63) == 0) sm[threadIdx.x >> 6] = s;
    __syncthreads();
    if (threadIdx.x == 0) atomicAdd(wsum, sm[0] + sm[1] + sm[2] + sm[3]);
}

// ---- kernel 2: ternarize W -> int8 {-1,0,1} -------------------------------
__global__ __launch_bounds__(256) void wtern(const float* __restrict__ w,
                                             const double* __restrict__ wsum,
                                             signed char* __restrict__ t) {
    int idx = blockIdx.x * 256 + threadIdx.x;
    float mean = (float)(wsum[0] * (1.0 / (double)WELEMS));
    float sw = 1.0f / fmaxf(mean, 1e-8f);
    float4 r = ((const float4*)w)[idx];
    float v[4] = { r.x, r.y, r.z, r.w };
    uint32_t p = 0;
#pragma unroll
    for (int j = 0; j < 4; j++) {
        int qi = (int)fminf(fmaxf(rintf(sw * v[j]), -1.0f), 1.0f);
        p |= ((uint32_t)(qi & 255)) << (8 * j);
    }
    ((uint32_t*)t)[idx] = p;
}

// ---- kernel 3: LayerNorm + per-token int8 quant ---------------------------
// one block (256 thr) per token; 8 fp32 elems/thread in registers.
__global__ __launch_bounds__(256) void ln_quant(const float* __restrict__ x,
                                                const double* __restrict__ wsum,
                                                signed char* __restrict__ q,
                                                float* __restrict__ scale) {
    int tok = blockIdx.x;
    const float4* xr = (const float4*)(x + (size_t)tok * DIN);
    float4 r1 = xr[threadIdx.x];            // cols 4t .. 4t+3
    float4 r2 = xr[256 + threadIdx.x];      // cols 1024+4t .. 1024+4t+3
    float v[8] = { r1.x, r1.y, r1.z, r1.w, r2.x, r2.y, r2.z, r2.w };
    float s = 0.0f, s2 = 0.0f;
#pragma unroll
    for (int j = 0; j < 8; j++) { s += v[j]; s2 = fmaf(v[j], v[j], s2); }
    for (int o = 32; o; o >>= 1) {
        s  += __shfl_down(s, o);
        s2 += __shfl_down(s2, o);
    }
    __shared__ float sm[12];
    int wid = threadIdx.x >> 6;
    if ((threadIdx.x & 63) == 0) { sm[wid] = s; sm[4 + wid] = s2; }
    __syncthreads();
    float S  = sm[0] + sm[1] + sm[2] + sm[3];
    float S2 = sm[4] + sm[5] + sm[6] + sm[7];
    float mu  = S * (1.0f / DIN);
    float var = S2 * (1.0f / DIN) - mu * mu;
    float rr  = 1.0f / sqrtf(var + 1e-8f);

    float md = 0.0f;
#pragma unroll
    for (int j = 0; j < 8; j++) md = fmaxf(md, fabsf(v[j] - mu));
    for (int o = 32; o; o >>= 1) md = fmaxf(md, __shfl_down(md, o));
    if ((threadIdx.x & 63) == 0) sm[8 + wid] = md;
    __syncthreads();
    md = fmaxf(fmaxf(sm[8], sm[9]), fmaxf(sm[10], sm[11]));

    float amax = fmaxf(rr * md, 1e-8f);     // max |y_norm|
    float sact = 127.0f / amax;

    uint32_t lo = 0, hi = 0;
#pragma unroll
    for (int j = 0; j < 4; j++) {
        float y = rr * (v[j] - mu);
        int qi = (int)fminf(fmaxf(rintf(sact * y), -128.0f), 127.0f);
        lo |= ((uint32_t)(qi & 255)) << (8 * j);
    }
#pragma unroll
    for (int j = 0; j < 4; j++) {
        float y = rr * (v[4 + j] - mu);
        int qi = (int)fminf(fmaxf(rintf(sact * y), -128.0f), 127.0f);
        hi |= ((uint32_t)(qi & 255)) << (8 * j);
    }
    uint32_t* qrow = (uint32_t*)(q + (size_t)tok * DIN);
    qrow[threadIdx.x]       = lo;           // cols 4t..4t+3
    qrow[256 + threadIdx.x] = hi;           // cols 1024+4t..

    if (threadIdx.x == 0) {
        float wmean = fmaxf((float)(wsum[0] * (1.0 / (double)WELEMS)), 1e-8f); // 1/s_w
        scale[tok] = (amax / 127.0f) * wmean;  // (1/s_act)*(1/s_w)
    }
}

// ---- kernel 4: int8 GEMM  C[m,n] = scale[m]*sum_k q[m,k]*t[n,k] + bias[n] -
// BM=BN=128, BK=128, 256 threads = 4 waves in 2x2, each wave 64x64 via
// 4x4 grid of mfma_i32_16x16x64_i8, 2 k-steps per tile.
// XOR-8 chunk swizzle applied at staging SOURCE (global_load_lds needs
// contiguous lane*16 LDS dest); fragment reads land 2-way bank alias = free.
__global__ __launch_bounds__(256, 2) void gemm_i8(const signed char* __restrict__ A,
                                                  const signed char* __restrict__ B,
                                                  const float* __restrict__ scale,
                                                  const float* __restrict__ bias,
                                                  float* __restrict__ C) {
    __shared__ signed char As[128 * 128];   // 16 KB, [row][128B of k], chunk-swizzled
    __shared__ signed char Bs[128 * 128];   // 16 KB

    const int tid  = threadIdx.x;
    const int bm   = blockIdx.x, bn = blockIdx.y;
    const int lane = tid & 63, wid = tid >> 6;
    const int quad = lane >> 4, l16 = lane & 15;
    const int waveM = (wid & 1) * 64, waveN = (wid >> 1) * 64;

    // staging: each insn moves 32 rows x 128B (256 lanes x 16B).
    // physical slot (tid&7) of row holds logical k-chunk (tid&7)^(row&7).
    const int srow   = tid >> 3;                    // 0..31
    const int schunk = (tid & 7) ^ (srow & 7);      // XOR-8 swizzle at source
    const signed char* aSrc = A + (size_t)(bm * 128 + srow) * DIN + schunk * 16;
    const signed char* bSrc = B + (size_t)(bn * 128 + srow) * DIN + schunk * 16;
    signed char* aDst = As + tid * 16;
    signed char* bDst = Bs + tid * 16;

    v4i acc[4][4] = {};

    for (int kt = 0; kt < DIN; kt += 128) {
        __syncthreads();                   // protect LDS from prev-iter readers
#pragma unroll
        for (int i = 0; i < 4; i++) {
            load_lds16(aSrc + kt + (size_t)(i * 32) * DIN, aDst + i * 4096);
            load_lds16(bSrc + kt + (size_t)(i * 32) * DIN, bDst + i * 4096);
        }
        __syncthreads();                   // drains vmcnt for global_load_lds

        v4i af[2][4], bf[2][4];
#pragma unroll
        for (int ks = 0; ks < 2; ks++) {
#pragma unroll
            for (int i = 0; i < 4; i++) {
                int rm = waveM + i * 16 + l16;
                af[ks][i] = *(const v4i*)&As[rm * 128 + (((ks * 4 + quad) ^ (rm & 7)) * 16)];
                int rn = waveN + i * 16 + l16;
                bf[ks][i] = *(const v4i*)&Bs[rn * 128 + (((ks * 4 + quad) ^ (rn & 7)) * 16)];
            }
        }

#pragma unroll
        for (int ks = 0; ks < 2; ks++)
#pragma unroll
            for (int mi = 0; mi < 4; mi++)
#pragma unroll
                for (int ni = 0; ni < 4; ni++)
                    acc[mi][ni] = __builtin_amdgcn_mfma_i32_16x16x64_i8(
                        af[ks][mi], bf[ks][ni], acc[mi][ni], 0, 0, 0);
    }

    // epilogue: C/D layout col=lane&15, row=quad*4+reg (dtype-independent)
    const int mBase = bm * 128 + waveM;
    const int nBase = bn * 128 + waveN;
#pragma unroll
    for (int ni = 0; ni < 4; ni++) {
        int n = nBase + ni * 16 + l16;
        float bz = bias[n];
#pragma unroll
        for (int mi = 0; mi < 4; mi++) {
#pragma unroll
            for (int rI = 0; rI < 4; rI++) {
                int m = mBase + mi * 16 + quad * 4 + rI;
                C[(size_t)m * DOUT + n] = fmaf(scale[m], (float)acc[mi][ni][rI], bz);
            }
        }
    }
}

extern "C" void kernel_launch(void* const* d_in, const int* in_sizes, int n_in,
                              void* d_out, int out_size, void* d_ws, size_t ws_size,
                              hipStream_t stream) {
    const float* x    = (const float*)d_in[0];   // f32 [16384, 2048]
    const float* w    = (const float*)d_in[1];   // f32 [2048, 2048]
    const float* bias = (const float*)d_in[2];   // f32 [2048]
    float* out = (float*)d_out;                  // f32 [16384, 2048]

    char* ws = (char*)d_ws;
    signed char* q     = (signed char*)ws;                               // 32 MB
    signed char* t     = (signed char*)(ws + (size_t)NTOK * DIN);        // 4 MB
    float*       scale = (float*)(ws + (size_t)NTOK * DIN + WELEMS);     // 64 KB
    double*      wsum  = (double*)(ws + (size_t)NTOK * DIN + WELEMS + NTOK * 4);

    zero_ws<<<1, 1, 0, stream>>>(wsum);
    wabs_sum<<<WELEMS / (256 * 4), 256, 0, stream>>>(w, wsum);
    wtern<<<WELEMS / (256 * 4), 256, 0, stream>>>(w, wsum, t);
    ln_quant<<<NTOK, 256, 0, stream>>>(x, wsum, q, scale);
    dim3 g(NTOK / 128, DOUT / 128);
    gemm_i8<<<g, 256, 0, stream>>>(q, t, scale, bias, out);
}

// Round 3
// 325.639 us; speedup vs baseline: 1.1733x; 1.1733x over previous
//
#include <hip/hip_runtime.h>
#include <stdint.h>

// Problem dims (fixed): x[4,4096,2048] f32, W[2048,2048] f32, bias[2048] f32
#define NTOK   16384
#define DIN    2048
#define DOUT   2048
#define WELEMS (DOUT * DIN)
#define NPART  512

typedef int v4i  __attribute__((ext_vector_type(4)));
typedef int v16i __attribute__((ext_vector_type(16)));

// async global->LDS, 16B per lane. LDS dest must be wave-uniform base + lane*16.
__device__ __forceinline__ void load_lds16(const void* g, void* s) {
    __builtin_amdgcn_global_load_lds(
        (const __attribute__((address_space(1))) void*)(uintptr_t)g,
        (__attribute__((address_space(3))) void*)(uintptr_t)s,
        16, 0, 0);
}

// ---- kernel 1a: per-block partial sums of |W| (no atomics) ----------------
__global__ __launch_bounds__(256) void wabs_partial(const float* __restrict__ w,
                                                    double* __restrict__ part) {
    double s = 0.0;
    int idx = blockIdx.x * 256 + threadIdx.x;
    const int stride = NPART * 256;                 // float4 stride
#pragma unroll
    for (int i = 0; i < WELEMS / 4 / stride; i++) { // 8 iters
        float4 r = ((const float4*)w)[idx + i * stride];
        s += (double)(fabsf(r.x) + fabsf(r.y)) + (double)(fabsf(r.z) + fabsf(r.w));
    }
    for (int o = 32; o; o >>= 1) s += __shfl_down(s, o);
    __shared__ double sm[4];
    if ((threadIdx.x & 63) == 0) sm[threadIdx.x >> 6] = s;
    __syncthreads();
    if (threadIdx.x == 0) part[blockIdx.x] = sm[0] + sm[1] + sm[2] + sm[3];
}

// ---- kernel 1b: reduce partials -> wsum (single block) --------------------
__global__ __launch_bounds__(256) void wabs_reduce(const double* __restrict__ part,
                                                   double* __restrict__ wsum) {
    double s = part[threadIdx.x] + part[256 + threadIdx.x];
    for (int o = 32; o; o >>= 1) s += __shfl_down(s, o);
    __shared__ double sm[4];
    if ((threadIdx.x & 63) == 0) sm[threadIdx.x >> 6] = s;
    __syncthreads();
    if (threadIdx.x == 0) wsum[0] = sm[0] + sm[1] + sm[2] + sm[3];
}

// ---- kernel 2: ternarize W -> int8 {-1,0,1} -------------------------------
__global__ __launch_bounds__(256) void wtern(const float* __restrict__ w,
                                             const double* __restrict__ wsum,
                                             signed char* __restrict__ t) {
    int idx = blockIdx.x * 256 + threadIdx.x;
    float mean = (float)(wsum[0] * (1.0 / (double)WELEMS));
    float sw = 1.0f / fmaxf(mean, 1e-8f);
    float4 r = ((const float4*)w)[idx];
    float v[4] = { r.x, r.y, r.z, r.w };
    uint32_t p = 0;
#pragma unroll
    for (int j = 0; j < 4; j++) {
        int qi = (int)fminf(fmaxf(rintf(sw * v[j]), -1.0f), 1.0f);
        p |= ((uint32_t)(qi & 255)) << (8 * j);
    }
    ((uint32_t*)t)[idx] = p;
}

// ---- kernel 3: LayerNorm + per-token int8 quant ---------------------------
// one block (256 thr) per token; 8 fp32 elems/thread in registers.
__global__ __launch_bounds__(256) void ln_quant(const float* __restrict__ x,
                                                const double* __restrict__ wsum,
                                                signed char* __restrict__ q,
                                                float* __restrict__ scale) {
    int tok = blockIdx.x;
    const float4* xr = (const float4*)(x + (size_t)tok * DIN);
    float4 r1 = xr[threadIdx.x];            // cols 4t .. 4t+3
    float4 r2 = xr[256 + threadIdx.x];      // cols 1024+4t .. 1024+4t+3
    float v[8] = { r1.x, r1.y, r1.z, r1.w, r2.x, r2.y, r2.z, r2.w };
    float s = 0.0f, s2 = 0.0f;
#pragma unroll
    for (int j = 0; j < 8; j++) { s += v[j]; s2 = fmaf(v[j], v[j], s2); }
    for (int o = 32; o; o >>= 1) {
        s  += __shfl_down(s, o);
        s2 += __shfl_down(s2, o);
    }
    __shared__ float sm[12];
    int wid = threadIdx.x >> 6;
    if ((threadIdx.x & 63) == 0) { sm[wid] = s; sm[4 + wid] = s2; }
    __syncthreads();
    float S  = sm[0] + sm[1] + sm[2] + sm[3];
    float S2 = sm[4] + sm[5] + sm[6] + sm[7];
    float mu  = S * (1.0f / DIN);
    float var = S2 * (1.0f / DIN) - mu * mu;
    float rr  = 1.0f / sqrtf(var + 1e-8f);

    float md = 0.0f;
#pragma unroll
    for (int j = 0; j < 8; j++) md = fmaxf(md, fabsf(v[j] - mu));
    for (int o = 32; o; o >>= 1) md = fmaxf(md, __shfl_down(md, o));
    if ((threadIdx.x & 63) == 0) sm[8 + wid] = md;
    __syncthreads();
    md = fmaxf(fmaxf(sm[8], sm[9]), fmaxf(sm[10], sm[11]));

    float amax = fmaxf(rr * md, 1e-8f);     // max |y_norm|
    float sact = 127.0f / amax;

    uint32_t lo = 0, hi = 0;
#pragma unroll
    for (int j = 0; j < 4; j++) {
        float y = rr * (v[j] - mu);
        int qi = (int)fminf(fmaxf(rintf(sact * y), -128.0f), 127.0f);
        lo |= ((uint32_t)(qi & 255)) << (8 * j);
    }
#pragma unroll
    for (int j = 0; j < 4; j++) {
        float y = rr * (v[4 + j] - mu);
        int qi = (int)fminf(fmaxf(rintf(sact * y), -128.0f), 127.0f);
        hi |= ((uint32_t)(qi & 255)) << (8 * j);
    }
    uint32_t* qrow = (uint32_t*)(q + (size_t)tok * DIN);
    qrow[threadIdx.x]       = lo;           // cols 4t..4t+3
    qrow[256 + threadIdx.x] = hi;           // cols 1024+4t..

    if (threadIdx.x == 0) {
        float wmean = fmaxf((float)(wsum[0] * (1.0 / (double)WELEMS)), 1e-8f); // 1/s_w
        scale[tok] = (amax / 127.0f) * wmean;  // (1/s_act)*(1/s_w)
    }
}

// ---- kernel 4: int8 GEMM  C[m,n] = scale[m]*sum_k q[m,k]*t[n,k] + bias[n] -
// BM=BN=128, BK=128, 256 threads = 4 waves in 2x2; each wave does 64x64 as
// a 2x2 grid of mfma_i32_32x32x32_i8 (16 MFMA + 16 ds_read_b128 per K-tile).
// XOR-8 chunk swizzle applied at staging SOURCE (global_load_lds needs
// contiguous lane*16 LDS dest); fragment reads land balanced across banks.
__global__ __launch_bounds__(256, 4) void gemm_i8(const signed char* __restrict__ A,
                                                  const signed char* __restrict__ B,
                                                  const float* __restrict__ scale,
                                                  const float* __restrict__ bias,
                                                  float* __restrict__ C) {
    __shared__ signed char As[128 * 128];   // 16 KB, [row][128B of k], chunk-swizzled
    __shared__ signed char Bs[128 * 128];   // 16 KB

    const int tid  = threadIdx.x;
    const int bm   = blockIdx.x, bn = blockIdx.y;
    const int lane = tid & 63, wid = tid >> 6;
    const int l31  = lane & 31, half = lane >> 5;
    const int waveM = (wid & 1) * 64, waveN = (wid >> 1) * 64;

    // staging: each insn moves 32 rows x 128B (256 lanes x 16B).
    // physical slot (tid&7) of row holds logical k-chunk (tid&7)^(row&7).
    const int srow   = tid >> 3;                    // 0..31
    const int schunk = (tid & 7) ^ (srow & 7);      // XOR-8 swizzle at source
    const signed char* aSrc = A + (size_t)(bm * 128 + srow) * DIN + schunk * 16;
    const signed char* bSrc = B + (size_t)(bn * 128 + srow) * DIN + schunk * 16;
    signed char* aDst = As + tid * 16;
    signed char* bDst = Bs + tid * 16;

    v16i acc[2][2] = {};

    const int rm0 = waveM + l31;        // A rows for mi=0 (mi=1: +32)
    const int rn0 = waveN + l31;        // B rows for ni=0
    const int sw8 = l31 & 7;            // row&7 (waveM/N, mi*32 are mult of 8)

    for (int kt = 0; kt < DIN; kt += 128) {
        __syncthreads();                   // protect LDS from prev-iter readers
#pragma unroll
        for (int i = 0; i < 4; i++) {
            load_lds16(aSrc + kt + (size_t)(i * 32) * DIN, aDst + i * 4096);
            load_lds16(bSrc + kt + (size_t)(i * 32) * DIN, bDst + i * 4096);
        }
        __syncthreads();                   // drains vmcnt for global_load_lds

#pragma unroll
        for (int ks = 0; ks < 4; ks++) {
            // A-frag (32x32, K=32): lane l: row = l&31, k = (l>>5)*16 + j
            const int c = ((ks * 2 + half) ^ sw8) * 16;
            v4i af[2], bf[2];
            af[0] = *(const v4i*)&As[rm0 * 128 + c];
            af[1] = *(const v4i*)&As[(rm0 + 32) * 128 + c];
            bf[0] = *(const v4i*)&Bs[rn0 * 128 + c];
            bf[1] = *(const v4i*)&Bs[(rn0 + 32) * 128 + c];
#pragma unroll
            for (int mi = 0; mi < 2; mi++)
#pragma unroll
                for (int ni = 0; ni < 2; ni++)
                    acc[mi][ni] = __builtin_amdgcn_mfma_i32_32x32x32_i8(
                        af[mi], bf[ni], acc[mi][ni], 0, 0, 0);
        }
    }

    // epilogue: 32x32 C/D layout col=lane&31, row=(reg&3)+8*(reg>>2)+4*(lane>>5)
    const int mBase = bm * 128 + waveM;
    const int nBase = bn * 128 + waveN;
#pragma unroll
    for (int ni = 0; ni < 2; ni++) {
        int n = nBase + ni * 32 + l31;
        float bz = bias[n];
#pragma unroll
        for (int mi = 0; mi < 2; mi++) {
#pragma unroll
            for (int reg = 0; reg < 16; reg++) {
                int row = (reg & 3) + 8 * (reg >> 2) + 4 * half;
                int m = mBase + mi * 32 + row;
                C[(size_t)m * DOUT + n] = fmaf(scale[m], (float)acc[mi][ni][reg], bz);
            }
        }
    }
}

extern "C" void kernel_launch(void* const* d_in, const int* in_sizes, int n_in,
                              void* d_out, int out_size, void* d_ws, size_t ws_size,
                              hipStream_t stream) {
    const float* x    = (const float*)d_in[0];   // f32 [16384, 2048]
    const float* w    = (const float*)d_in[1];   // f32 [2048, 2048]
    const float* bias = (const float*)d_in[2];   // f32 [2048]
    float* out = (float*)d_out;                  // f32 [16384, 2048]

    char* ws = (char*)d_ws;
    signed char* q     = (signed char*)ws;                               // 32 MB
    signed char* t     = (signed char*)(ws + (size_t)NTOK * DIN);        // 4 MB
    float*       scale = (float*)(ws + (size_t)NTOK * DIN + WELEMS);     // 64 KB
    char*        tail  = ws + (size_t)NTOK * DIN + WELEMS + NTOK * 4;
    double*      wsum  = (double*)tail;                                  // 8 B
    double*      part  = (double*)(tail + 4096);                         // 4 KB

    wabs_partial<<<NPART, 256, 0, stream>>>(w, part);
    wabs_reduce<<<1, 256, 0, stream>>>(part, wsum);
    wtern<<<WELEMS / (256 * 4), 256, 0, stream>>>(w, wsum, t);
    ln_quant<<<NTOK, 256, 0, stream>>>(x, wsum, q, scale);
    dim3 g(NTOK / 128, DOUT / 128);
    gemm_i8<<<g, 256, 0, stream>>>(q, t, scale, bias, out);
}

// Round 4
// 314.347 us; speedup vs baseline: 1.2154x; 1.0359x over previous
//
#include <hip/hip_runtime.h>
#include <stdint.h>

// Problem dims (fixed): x[4,4096,2048] f32, W[2048,2048] f32, bias[2048] f32
#define NTOK   16384
#define DIN    2048
#define DOUT   2048
#define WELEMS (DOUT * DIN)
#define NPART  512

typedef int v4i  __attribute__((ext_vector_type(4)));
typedef int v16i __attribute__((ext_vector_type(16)));

// async global->LDS, 16B per lane. LDS dest must be wave-uniform base + lane*16.
__device__ __forceinline__ void load_lds16(const void* g, void* s) {
    __builtin_amdgcn_global_load_lds(
        (const __attribute__((address_space(1))) void*)(uintptr_t)g,
        (__attribute__((address_space(3))) void*)(uintptr_t)s,
        16, 0, 0);
}

// ---- kernel 1a: per-block partial sums of |W| (no atomics) ----------------
__global__ __launch_bounds__(256) void wabs_partial(const float* __restrict__ w,
                                                    double* __restrict__ part) {
    double s = 0.0;
    int idx = blockIdx.x * 256 + threadIdx.x;
    const int stride = NPART * 256;                 // float4 stride
#pragma unroll
    for (int i = 0; i < WELEMS / 4 / stride; i++) { // 8 iters
        float4 r = ((const float4*)w)[idx + i * stride];
        s += (double)(fabsf(r.x) + fabsf(r.y)) + (double)(fabsf(r.z) + fabsf(r.w));
    }
    for (int o = 32; o; o >>= 1) s += __shfl_down(s, o);
    __shared__ double sm[4];
    if ((threadIdx.x & 63) == 0) sm[threadIdx.x >> 6] = s;
    __syncthreads();
    if (threadIdx.x == 0) part[blockIdx.x] = sm[0] + sm[1] + sm[2] + sm[3];
}

// ---- kernel 1b: reduce partials -> wsum (single block) --------------------
__global__ __launch_bounds__(256) void wabs_reduce(const double* __restrict__ part,
                                                   double* __restrict__ wsum) {
    double s = part[threadIdx.x] + part[256 + threadIdx.x];
    for (int o = 32; o; o >>= 1) s += __shfl_down(s, o);
    __shared__ double sm[4];
    if ((threadIdx.x & 63) == 0) sm[threadIdx.x >> 6] = s;
    __syncthreads();
    if (threadIdx.x == 0) wsum[0] = sm[0] + sm[1] + sm[2] + sm[3];
}

// ---- kernel 2: ternarize W -> int8 {-1,0,1} -------------------------------
__global__ __launch_bounds__(256) void wtern(const float* __restrict__ w,
                                             const double* __restrict__ wsum,
                                             signed char* __restrict__ t) {
    int idx = blockIdx.x * 256 + threadIdx.x;
    float mean = (float)(wsum[0] * (1.0 / (double)WELEMS));
    float sw = 1.0f / fmaxf(mean, 1e-8f);
    float4 r = ((const float4*)w)[idx];
    float v[4] = { r.x, r.y, r.z, r.w };
    uint32_t p = 0;
#pragma unroll
    for (int j = 0; j < 4; j++) {
        int qi = (int)fminf(fmaxf(rintf(sw * v[j]), -1.0f), 1.0f);
        p |= ((uint32_t)(qi & 255)) << (8 * j);
    }
    ((uint32_t*)t)[idx] = p;
}

// ---- kernel 3: LayerNorm + per-token int8 quant ---------------------------
__global__ __launch_bounds__(256) void ln_quant(const float* __restrict__ x,
                                                const double* __restrict__ wsum,
                                                signed char* __restrict__ q,
                                                float* __restrict__ scale) {
    int tok = blockIdx.x;
    const float4* xr = (const float4*)(x + (size_t)tok * DIN);
    float4 r1 = xr[threadIdx.x];            // cols 4t .. 4t+3
    float4 r2 = xr[256 + threadIdx.x];      // cols 1024+4t .. 1024+4t+3
    float v[8] = { r1.x, r1.y, r1.z, r1.w, r2.x, r2.y, r2.z, r2.w };
    float s = 0.0f, s2 = 0.0f;
#pragma unroll
    for (int j = 0; j < 8; j++) { s += v[j]; s2 = fmaf(v[j], v[j], s2); }
    for (int o = 32; o; o >>= 1) {
        s  += __shfl_down(s, o);
        s2 += __shfl_down(s2, o);
    }
    __shared__ float sm[12];
    int wid = threadIdx.x >> 6;
    if ((threadIdx.x & 63) == 0) { sm[wid] = s; sm[4 + wid] = s2; }
    __syncthreads();
    float S  = sm[0] + sm[1] + sm[2] + sm[3];
    float S2 = sm[4] + sm[5] + sm[6] + sm[7];
    float mu  = S * (1.0f / DIN);
    float var = S2 * (1.0f / DIN) - mu * mu;
    float rr  = 1.0f / sqrtf(var + 1e-8f);

    float md = 0.0f;
#pragma unroll
    for (int j = 0; j < 8; j++) md = fmaxf(md, fabsf(v[j] - mu));
    for (int o = 32; o; o >>= 1) md = fmaxf(md, __shfl_down(md, o));
    if ((threadIdx.x & 63) == 0) sm[8 + wid] = md;
    __syncthreads();
    md = fmaxf(fmaxf(sm[8], sm[9]), fmaxf(sm[10], sm[11]));

    float amax = fmaxf(rr * md, 1e-8f);     // max |y_norm|
    float sact = 127.0f / amax;

    uint32_t lo = 0, hi = 0;
#pragma unroll
    for (int j = 0; j < 4; j++) {
        float y = rr * (v[j] - mu);
        int qi = (int)fminf(fmaxf(rintf(sact * y), -128.0f), 127.0f);
        lo |= ((uint32_t)(qi & 255)) << (8 * j);
    }
#pragma unroll
    for (int j = 0; j < 4; j++) {
        float y = rr * (v[4 + j] - mu);
        int qi = (int)fminf(fmaxf(rintf(sact * y), -128.0f), 127.0f);
        hi |= ((uint32_t)(qi & 255)) << (8 * j);
    }
    uint32_t* qrow = (uint32_t*)(q + (size_t)tok * DIN);
    qrow[threadIdx.x]       = lo;
    qrow[256 + threadIdx.x] = hi;

    if (threadIdx.x == 0) {
        float wmean = fmaxf((float)(wsum[0] * (1.0 / (double)WELEMS)), 1e-8f); // 1/s_w
        scale[tok] = (amax / 127.0f) * wmean;  // (1/s_act)*(1/s_w)
    }
}

// ---- kernel 4: int8 GEMM  C[m,n] = scale[m]*sum_k q[m,k]*t[n,k] + bias[n] -
// BM=BN=128, BK=128, 256 thr = 4 waves (2x2); wave 64x64 via 2x2 of
// mfma_i32_32x32x32_i8. Swizzle: physical slot of logical 16B chunk c in
// row r is  c ^ (r&7) ^ ((r>>3)&3)  — bijective per row, and distinct
// across BOTH consecutive-8 and stride-8 lane groups of the b128 frag
// read (R3 measured: stride-8 grouping is the real conflict model; slot
// depending only on lane bit5 gave exactly +4 cyc/read).
__global__ __launch_bounds__(256, 5) void gemm_i8(const signed char* __restrict__ A,
                                                  const signed char* __restrict__ B,
                                                  const float* __restrict__ scale,
                                                  const float* __restrict__ bias,
                                                  float* __restrict__ C) {
    __shared__ signed char As[128 * 128];   // 16 KB
    __shared__ signed char Bs[128 * 128];   // 16 KB

    const int tid  = threadIdx.x;
    const int bn   = blockIdx.x, bm = blockIdx.y;   // N-fastest: blocks sharing
    const int lane = tid & 63, wid = tid >> 6;      // a Q-tile launch together
    const int l31  = lane & 31, half = lane >> 5;
    const int waveM = (wid & 1) * 64, waveN = (wid >> 1) * 64;

    // staging: each insn moves 32 rows x 128B (256 lanes x 16B).
    const int srow   = tid >> 3;                                  // 0..31
    const int schunk = (tid & 7) ^ (srow & 7) ^ ((srow >> 3) & 3);// logical chunk at this slot
    const signed char* aSrc = A + (size_t)(bm * 128 + srow) * DIN + schunk * 16;
    const signed char* bSrc = B + (size_t)(bn * 128 + srow) * DIN + schunk * 16;
    signed char* aDst = As + tid * 16;
    signed char* bDst = Bs + tid * 16;

    v16i acc[2][2] = {};

    const int rm0 = waveM + l31;        // A rows for mi=0 (mi=1: +32)
    const int rn0 = waveN + l31;        // B rows for ni=0
    const int sw  = (l31 & 7) ^ ((l31 >> 3) & 3);  // row-derived swizzle bits
                                        // (invariant under +32/+64 row offsets)

    for (int kt = 0; kt < DIN; kt += 128) {
        __syncthreads();                   // protect LDS from prev-iter readers
#pragma unroll
        for (int i = 0; i < 4; i++) {
            load_lds16(aSrc + kt + (size_t)(i * 32) * DIN, aDst + i * 4096);
            load_lds16(bSrc + kt + (size_t)(i * 32) * DIN, bDst + i * 4096);
        }
        __syncthreads();                   // drains vmcnt for global_load_lds

#pragma unroll
        for (int ks = 0; ks < 4; ks++) {
            // A-frag (32x32, K=32): lane l: row = l&31, k = (l>>5)*16 + j
            const int c = (((ks * 2 + half) ^ sw)) * 16;
            v4i af[2], bf[2];
            af[0] = *(const v4i*)&As[rm0 * 128 + c];
            af[1] = *(const v4i*)&As[(rm0 + 32) * 128 + c];
            bf[0] = *(const v4i*)&Bs[rn0 * 128 + c];
            bf[1] = *(const v4i*)&Bs[(rn0 + 32) * 128 + c];
#pragma unroll
            for (int mi = 0; mi < 2; mi++)
#pragma unroll
                for (int ni = 0; ni < 2; ni++)
                    acc[mi][ni] = __builtin_amdgcn_mfma_i32_32x32x32_i8(
                        af[mi], bf[ni], acc[mi][ni], 0, 0, 0);
        }
    }

    // epilogue: 32x32 C/D layout col=lane&31, row=(reg&3)+8*(reg>>2)+4*(lane>>5)
    const int mBase = bm * 128 + waveM;
    const int nBase = bn * 128 + waveN;
#pragma unroll
    for (int ni = 0; ni < 2; ni++) {
        int n = nBase + ni * 32 + l31;
        float bz = bias[n];
#pragma unroll
        for (int mi = 0; mi < 2; mi++) {
#pragma unroll
            for (int reg = 0; reg < 16; reg++) {
                int row = (reg & 3) + 8 * (reg >> 2) + 4 * half;
                int m = mBase + mi * 32 + row;
                C[(size_t)m * DOUT + n] = fmaf(scale[m], (float)acc[mi][ni][reg], bz);
            }
        }
    }
}

extern "C" void kernel_launch(void* const* d_in, const int* in_sizes, int n_in,
                              void* d_out, int out_size, void* d_ws, size_t ws_size,
                              hipStream_t stream) {
    const float* x    = (const float*)d_in[0];   // f32 [16384, 2048]
    const float* w    = (const float*)d_in[1];   // f32 [2048, 2048]
    const float* bias = (const float*)d_in[2];   // f32 [2048]
    float* out = (float*)d_out;                  // f32 [16384, 2048]

    char* ws = (char*)d_ws;
    signed char* q     = (signed char*)ws;                               // 32 MB
    signed char* t     = (signed char*)(ws + (size_t)NTOK * DIN);        // 4 MB
    float*       scale = (float*)(ws + (size_t)NTOK * DIN + WELEMS);     // 64 KB
    char*        tail  = ws + (size_t)NTOK * DIN + WELEMS + NTOK * 4;
    double*      wsum  = (double*)tail;                                  // 8 B
    double*      part  = (double*)(tail + 4096);                         // 4 KB

    wabs_partial<<<NPART, 256, 0, stream>>>(w, part);
    wabs_reduce<<<1, 256, 0, stream>>>(part, wsum);
    wtern<<<WELEMS / (256 * 4), 256, 0, stream>>>(w, wsum, t);
    ln_quant<<<NTOK, 256, 0, stream>>>(x, wsum, q, scale);
    dim3 g(DOUT / 128, NTOK / 128);   // N-fastest for Q-tile L2 reuse
    gemm_i8<<<g, 256, 0, stream>>>(q, t, scale, bias, out);
}